// Round 1
// baseline (3157.748 us; speedup 1.0000x reference)
//
#include <hip/hip_runtime.h>
#include <math.h>

// Problem constants
#define BATCH 4
#define SEQ   1024
#define DIM   1024
#define HEADS 16
#define HD    64
#define NEXP  2
#define NSLOT 512
#define ES    1024       // NEXP*NSLOT
#define HID   4096
#define LNEPS 1e-5f
#define NTOK  (BATCH*SEQ)

typedef long long ll;

// ---------------------------------------------------------------------------
// Generic fp32 GEMM, C[M,N] = A[M,K] @ B[K,N] (+bias) (+gelu)
// 64x64 tile, 256 threads, 4x4 microtile, K-tile 16.
// Batched via blockIdx.z decomposed as z1=z/Z2, z2=z%Z2 with stride pairs.
// LDS rows padded to 68 floats: 16B-aligned rows -> ds_read_b128, <=2-way banks.
// ---------------------------------------------------------------------------
__global__ __launch_bounds__(256) void gemm_nn(
    const float* __restrict__ A, int lda, ll sA1, ll sA2,
    const float* __restrict__ B, int ldb, ll sB1, ll sB2,
    const float* __restrict__ bias, ll sb1, ll sb2,
    float* __restrict__ C, int ldc, ll sC1, ll sC2,
    int M, int N, int K, int Z2, int act)
{
    __shared__ float As[16][68];
    __shared__ float Bs[16][68];
    int z1 = blockIdx.z / Z2, z2 = blockIdx.z % Z2;
    A += z1 * sA1 + z2 * sA2;
    B += z1 * sB1 + z2 * sB2;
    C += z1 * sC1 + z2 * sC2;
    const int t = threadIdx.x;
    const int m0 = blockIdx.y * 64, n0 = blockIdx.x * 64;
    const int tx = t & 15, ty = t >> 4;
    float acc[4][4] = {};
    for (int k0 = 0; k0 < K; k0 += 16) {
        #pragma unroll
        for (int i = 0; i < 4; i++) {             // A tile 64x16 -> As[k][m]
            int lin = t + 256 * i;
            int r = lin >> 4, c = lin & 15;
            As[c][r] = A[(ll)(m0 + r) * lda + k0 + c];
        }
        #pragma unroll
        for (int i = 0; i < 4; i++) {             // B tile 16x64 -> Bs[k][n]
            int lin = t + 256 * i;
            int r = lin >> 6, c = lin & 63;
            Bs[r][c] = B[(ll)(k0 + r) * ldb + n0 + c];
        }
        __syncthreads();
        #pragma unroll
        for (int kk = 0; kk < 16; kk++) {
            float a[4], b[4];
            #pragma unroll
            for (int i = 0; i < 4; i++) a[i] = As[kk][ty * 4 + i];
            #pragma unroll
            for (int j = 0; j < 4; j++) b[j] = Bs[kk][tx * 4 + j];
            #pragma unroll
            for (int i = 0; i < 4; i++)
                #pragma unroll
                for (int j = 0; j < 4; j++)
                    acc[i][j] = fmaf(a[i], b[j], acc[i][j]);
        }
        __syncthreads();
    }
    const float* bz = bias ? (bias + z1 * sb1 + z2 * sb2) : nullptr;
    #pragma unroll
    for (int i = 0; i < 4; i++) {
        int m = m0 + ty * 4 + i;
        #pragma unroll
        for (int j = 0; j < 4; j++) {
            int n = n0 + tx * 4 + j;
            float v = acc[i][j];
            if (bz) v += bz[n];
            if (act) {  // jax.nn.gelu approximate=True (tanh)
                float x3 = v * v * v;
                v = 0.5f * v * (1.f + tanhf(0.7978845608028654f * (v + 0.044715f * x3)));
            }
            C[(ll)m * ldc + n] = v;
        }
    }
}

// C[M,N] = alpha * A[M,K] @ B[N,K]^T   (QK^T; K small, no bias)
__global__ __launch_bounds__(256) void gemm_abt(
    const float* __restrict__ A, int lda, ll sA1, ll sA2,
    const float* __restrict__ B, int ldb, ll sB1, ll sB2,
    float* __restrict__ C, int ldc, ll sC1, ll sC2,
    int M, int N, int K, int Z2, float alpha)
{
    __shared__ float As[16][68];
    __shared__ float Bs[16][68];
    int z1 = blockIdx.z / Z2, z2 = blockIdx.z % Z2;
    A += z1 * sA1 + z2 * sA2;
    B += z1 * sB1 + z2 * sB2;
    C += z1 * sC1 + z2 * sC2;
    const int t = threadIdx.x;
    const int m0 = blockIdx.y * 64, n0 = blockIdx.x * 64;
    const int tx = t & 15, ty = t >> 4;
    float acc[4][4] = {};
    for (int k0 = 0; k0 < K; k0 += 16) {
        #pragma unroll
        for (int i = 0; i < 4; i++) {             // A rows -> As[k][m]
            int lin = t + 256 * i;
            int r = lin >> 4, c = lin & 15;
            As[c][r] = A[(ll)(m0 + r) * lda + k0 + c];
        }
        #pragma unroll
        for (int i = 0; i < 4; i++) {             // B rows (transposed) -> Bs[k][n]
            int lin = t + 256 * i;
            int r = lin >> 4, c = lin & 15;
            Bs[c][r] = B[(ll)(n0 + r) * ldb + k0 + c];
        }
        __syncthreads();
        #pragma unroll
        for (int kk = 0; kk < 16; kk++) {
            float a[4], b[4];
            #pragma unroll
            for (int i = 0; i < 4; i++) a[i] = As[kk][ty * 4 + i];
            #pragma unroll
            for (int j = 0; j < 4; j++) b[j] = Bs[kk][tx * 4 + j];
            #pragma unroll
            for (int i = 0; i < 4; i++)
                #pragma unroll
                for (int j = 0; j < 4; j++)
                    acc[i][j] = fmaf(a[i], b[j], acc[i][j]);
        }
        __syncthreads();
    }
    #pragma unroll
    for (int i = 0; i < 4; i++) {
        int m = m0 + ty * 4 + i;
        #pragma unroll
        for (int j = 0; j < 4; j++) {
            int n = n0 + tx * 4 + j;
            C[(ll)m * ldc + n] = alpha * acc[i][j];
        }
    }
}

// C[M,N] = A[K,M]^T @ B[K,N]   (slots = dispatch^T @ x1; no bias)
__global__ __launch_bounds__(256) void gemm_atb(
    const float* __restrict__ A, int lda, ll sA1, ll sA2,
    const float* __restrict__ B, int ldb, ll sB1, ll sB2,
    float* __restrict__ C, int ldc, ll sC1, ll sC2,
    int M, int N, int K, int Z2)
{
    __shared__ float As[16][68];
    __shared__ float Bs[16][68];
    int z1 = blockIdx.z / Z2, z2 = blockIdx.z % Z2;
    A += z1 * sA1 + z2 * sA2;
    B += z1 * sB1 + z2 * sB2;
    C += z1 * sC1 + z2 * sC2;
    const int t = threadIdx.x;
    const int m0 = blockIdx.y * 64, n0 = blockIdx.x * 64;
    const int tx = t & 15, ty = t >> 4;
    float acc[4][4] = {};
    for (int k0 = 0; k0 < K; k0 += 16) {
        #pragma unroll
        for (int i = 0; i < 4; i++) {             // A tile 16x64 -> As[k][m]
            int lin = t + 256 * i;
            int r = lin >> 6, c = lin & 63;
            As[r][c] = A[(ll)(k0 + r) * lda + m0 + c];
        }
        #pragma unroll
        for (int i = 0; i < 4; i++) {             // B tile 16x64 -> Bs[k][n]
            int lin = t + 256 * i;
            int r = lin >> 6, c = lin & 63;
            Bs[r][c] = B[(ll)(k0 + r) * ldb + n0 + c];
        }
        __syncthreads();
        #pragma unroll
        for (int kk = 0; kk < 16; kk++) {
            float a[4], b[4];
            #pragma unroll
            for (int i = 0; i < 4; i++) a[i] = As[kk][ty * 4 + i];
            #pragma unroll
            for (int j = 0; j < 4; j++) b[j] = Bs[kk][tx * 4 + j];
            #pragma unroll
            for (int i = 0; i < 4; i++)
                #pragma unroll
                for (int j = 0; j < 4; j++)
                    acc[i][j] = fmaf(a[i], b[j], acc[i][j]);
        }
        __syncthreads();
    }
    #pragma unroll
    for (int i = 0; i < 4; i++) {
        int m = m0 + ty * 4 + i;
        #pragma unroll
        for (int j = 0; j < 4; j++) {
            int n = n0 + tx * 4 + j;
            C[(ll)m * ldc + n] = acc[i][j];
        }
    }
}

// ---------------------------------------------------------------------------
// Attention softmax over m for one batch:
//   p layout (h,n,m), normalized in place (for the AV GEMM) and ALSO written
//   contiguously to attn_out in (n,m,h) layout (the required bnmh output).
// One block per n; each of 4 waves owns one head per pass (wave-only reduce).
// 64KB LDS transpose tile; XOR swizzle (m ^ ((h&7)<<2)) keeps banks <=2-way.
// ---------------------------------------------------------------------------
__global__ __launch_bounds__(256) void attn_softmax(
    float* __restrict__ p, float* __restrict__ attn_out)
{
    __shared__ float tile[16 * 1024];
    const int n = blockIdx.x;
    const int lane = threadIdx.x & 63, w = threadIdx.x >> 6;
    for (int hq = 0; hq < 4; hq++) {
        int h = hq * 4 + w;
        float* row = p + ((ll)h * SEQ + n) * SEQ;
        float v[16];
        float m = -3.0e38f;
        #pragma unroll
        for (int j = 0; j < 16; j++) { v[j] = row[lane + 64 * j]; m = fmaxf(m, v[j]); }
        #pragma unroll
        for (int o = 32; o; o >>= 1) m = fmaxf(m, __shfl_xor(m, o));
        float s = 0.f;
        #pragma unroll
        for (int j = 0; j < 16; j++) { v[j] = __expf(v[j] - m); s += v[j]; }
        #pragma unroll
        for (int o = 32; o; o >>= 1) s += __shfl_xor(s, o);
        float inv = 1.f / s;
        int sw = (h & 7) << 2;
        #pragma unroll
        for (int j = 0; j < 16; j++) {
            float e = v[j] * inv;
            int mm = lane + 64 * j;
            row[mm] = e;
            tile[h * 1024 + (mm ^ sw)] = e;
        }
    }
    __syncthreads();
    float* outp = attn_out + (ll)n * SEQ * HEADS;
    for (int o = threadIdx.x; o < SEQ * HEADS; o += 256) {
        int mm = o >> 4, h = o & 15;
        outp[o] = tile[h * 1024 + (mm ^ ((h & 7) << 2))];
    }
}

// ---------------------------------------------------------------------------
// LayerNorm: out_row = LN(a_row + coef*b_row) * g + beta    (rows of DIM)
// ---------------------------------------------------------------------------
__global__ __launch_bounds__(256) void ln_kernel(
    const float* __restrict__ a, const float* __restrict__ b, float coef,
    const float* __restrict__ g, const float* __restrict__ beta,
    float* __restrict__ out)
{
    const int row = blockIdx.x;
    const float* ar = a + (ll)row * DIM;
    const float* br = b + (ll)row * DIM;
    float v[4];
    float s1 = 0.f, s2 = 0.f;
    #pragma unroll
    for (int j = 0; j < 4; j++) {
        int i = threadIdx.x + 256 * j;
        v[j] = ar[i] + coef * br[i];
        s1 += v[j]; s2 += v[j] * v[j];
    }
    __shared__ float red[8];
    #pragma unroll
    for (int o = 32; o; o >>= 1) { s1 += __shfl_xor(s1, o); s2 += __shfl_xor(s2, o); }
    int w = threadIdx.x >> 6;
    if ((threadIdx.x & 63) == 0) { red[w] = s1; red[4 + w] = s2; }
    __syncthreads();
    s1 = red[0] + red[1] + red[2] + red[3];
    s2 = red[4] + red[5] + red[6] + red[7];
    float mu = s1 * (1.f / DIM);
    float var = s2 * (1.f / DIM) - mu * mu;
    float rs = rsqrtf(var + LNEPS);
    float* orow = out + (ll)row * DIM;
    #pragma unroll
    for (int j = 0; j < 4; j++) {
        int i = threadIdx.x + 256 * j;
        orow[i] = (v[j] - mu) * rs * g[i] + beta[i];
    }
}

// ---------------------------------------------------------------------------
// dispatch = softmax over n (axis=1) of logits (b,n,es): column softmax.
// grid (4, 16); block = 64 cols x 4 row-groups.
// ---------------------------------------------------------------------------
__global__ __launch_bounds__(256) void col_softmax(
    const float* __restrict__ logits, float* __restrict__ disp)
{
    const int b = blockIdx.x, cc = blockIdx.y;
    const int cl = threadIdx.x & 63;
    const int c = cc * 64 + cl;
    const int rg = threadIdx.x >> 6;
    const float* L = logits + (ll)b * SEQ * ES + c;
    float* D = disp + (ll)b * SEQ * ES + c;
    __shared__ float red[4][64];
    float m = -3.0e38f;
    for (int n = rg; n < SEQ; n += 4) m = fmaxf(m, L[(ll)n * ES]);
    red[rg][cl] = m;
    __syncthreads();
    m = fmaxf(fmaxf(red[0][cl], red[1][cl]), fmaxf(red[2][cl], red[3][cl]));
    __syncthreads();
    float s = 0.f;
    for (int n = rg; n < SEQ; n += 4) {
        float e = __expf(L[(ll)n * ES] - m);
        D[(ll)n * ES] = e;
        s += e;
    }
    red[rg][cl] = s;
    __syncthreads();
    s = red[0][cl] + red[1][cl] + red[2][cl] + red[3][cl];
    float inv = 1.f / s;
    for (int n = rg; n < SEQ; n += 4) D[(ll)n * ES] *= inv;
}

// combine = softmax over es (rows of 1024)
__global__ __launch_bounds__(256) void row_softmax(
    const float* __restrict__ logits, float* __restrict__ comb)
{
    const int row = blockIdx.x;
    const float* L = logits + (ll)row * ES;
    float* O = comb + (ll)row * ES;
    float v[4];
    float m = -3.0e38f;
    #pragma unroll
    for (int j = 0; j < 4; j++) { v[j] = L[threadIdx.x + 256 * j]; m = fmaxf(m, v[j]); }
    __shared__ float red[8];
    #pragma unroll
    for (int o = 32; o; o >>= 1) m = fmaxf(m, __shfl_xor(m, o));
    int w = threadIdx.x >> 6;
    if ((threadIdx.x & 63) == 0) red[w] = m;
    __syncthreads();
    m = fmaxf(fmaxf(red[0], red[1]), fmaxf(red[2], red[3]));
    __syncthreads();
    float s = 0.f;
    #pragma unroll
    for (int j = 0; j < 4; j++) { v[j] = __expf(v[j] - m); s += v[j]; }
    #pragma unroll
    for (int o = 32; o; o >>= 1) s += __shfl_xor(s, o);
    if ((threadIdx.x & 63) == 0) red[4 + w] = s;
    __syncthreads();
    s = red[4] + red[5] + red[6] + red[7];
    float inv = 1.f / s;
    #pragma unroll
    for (int j = 0; j < 4; j++) O[threadIdx.x + 256 * j] = v[j] * inv;
}

// ---------------------------------------------------------------------------
extern "C" void kernel_launch(void* const* d_in, const int* in_sizes, int n_in,
                              void* d_out, int out_size, void* d_ws, size_t ws_size,
                              hipStream_t stream)
{
    const float* x   = (const float*)d_in[0];
    const float* Wq  = (const float*)d_in[1];
    const float* bq  = (const float*)d_in[2];
    const float* Wkv = (const float*)d_in[3];
    const float* bkv = (const float*)d_in[4];
    const float* Wp  = (const float*)d_in[5];
    const float* bp  = (const float*)d_in[6];
    const float* g1  = (const float*)d_in[7];
    const float* b1  = (const float*)d_in[8];
    const float* phi = (const float*)d_in[9];
    const float* We1 = (const float*)d_in[10];
    const float* be1 = (const float*)d_in[11];
    const float* We2 = (const float*)d_in[12];
    const float* be2 = (const float*)d_in[13];
    const float* g2  = (const float*)d_in[14];
    const float* b2  = (const float*)d_in[15];

    float* out_y    = (float*)d_out;
    float* out_attn = out_y + (ll)BATCH * SEQ * DIM;

    // Workspace layout (floats), 48M floats = 192 MB total, with region reuse:
    const ll M1 = 1024 * 1024;
    float* ws    = (float*)d_ws;
    float* p     = ws;                 // 16M: per-batch scores (h,n,m) -> later hmid
    float* logit = ws + 16 * M1;       //  4M: (kv region reuse)
    float* disp  = ws + 20 * M1;       //  4M
    float* kv    = ws + 16 * M1;       //  8M: lives until last AV, then logit/disp
    float* q     = ws + 24 * M1;       //  4M -> later comb
    float* comb  = ws + 24 * M1;
    float* x1    = ws + 28 * M1;       //  4M
    float* po    = ws + 32 * M1;       //  4M -> later moe_out
    float* moe   = ws + 32 * M1;
    float* slots = ws + 36 * M1;       //  4M
    float* ymoe  = ws + 40 * M1;       //  4M
    float* ao    = ws + 44 * M1;       //  4M
    float* hmid  = ws;                 // 16M (reuses p)

    dim3 blk(256);

    // 1-2: QKV projections
    gemm_nn<<<dim3(16, 64, 1), blk, 0, stream>>>(
        x, DIM, 0, 0, Wq, DIM, 0, 0, bq, 0, 0, q, DIM, 0, 0,
        NTOK, DIM, DIM, 1, 0);
    gemm_nn<<<dim3(32, 64, 1), blk, 0, stream>>>(
        x, DIM, 0, 0, Wkv, 2 * DIM, 0, 0, bkv, 0, 0, kv, 2 * DIM, 0, 0,
        NTOK, 2 * DIM, DIM, 1, 0);

    // 3-5: attention per batch (p buffer reused serially across b)
    for (int b = 0; b < BATCH; b++) {
        const float* qb = q + (ll)b * SEQ * DIM;
        const float* kb = kv + (ll)b * SEQ * 2 * DIM;        // k at col 0
        const float* vb = kb + DIM;                          // v at col DIM
        // scores: p[h,n,m] = 0.125 * q_bh @ k_bh^T
        gemm_abt<<<dim3(16, 16, 16), blk, 0, stream>>>(
            qb, DIM, 0, 64, kb, 2 * DIM, 0, 64,
            p, SEQ, 0, (ll)SEQ * SEQ,
            SEQ, SEQ, HD, 16, 0.125f);
        // softmax over m; writes normalized p in place + bnmh output
        attn_softmax<<<dim3(SEQ), blk, 0, stream>>>(
            p, out_attn + (ll)b * SEQ * SEQ * HEADS);
        // ao[n, h*64+d] = p_h @ v_h
        gemm_nn<<<dim3(1, 16, 16), blk, 0, stream>>>(
            p, SEQ, 0, (ll)SEQ * SEQ, vb, 2 * DIM, 0, 64,
            nullptr, 0, 0,
            ao + (ll)b * SEQ * DIM, DIM, 0, 64,
            SEQ, HD, SEQ, 16, 0);
    }

    // 6: output projection (+bp)
    gemm_nn<<<dim3(16, 64, 1), blk, 0, stream>>>(
        ao, DIM, 0, 0, Wp, DIM, 0, 0, bp, 0, 0, po, DIM, 0, 0,
        NTOK, DIM, DIM, 1, 0);
    // 7: x1 = LN(po + x)
    ln_kernel<<<dim3(NTOK), blk, 0, stream>>>(po, x, 1.0f, g1, b1, x1);

    // 8: moe logits = x1 @ phi  (phi: (D, E*S))
    gemm_nn<<<dim3(16, 64, 1), blk, 0, stream>>>(
        x1, DIM, 0, 0, phi, ES, 0, 0, nullptr, 0, 0, logit, ES, 0, 0,
        NTOK, ES, DIM, 1, 0);
    // 9: dispatch = softmax over n; 10: combine = softmax over es
    col_softmax<<<dim3(BATCH, 16), blk, 0, stream>>>(logit, disp);
    row_softmax<<<dim3(NTOK), blk, 0, stream>>>(logit, comb);

    // 11: slots[b] = dispatch[b]^T @ x1[b]   (ES x DIM per batch)
    gemm_atb<<<dim3(16, 16, BATCH), blk, 0, stream>>>(
        disp, ES, (ll)SEQ * ES, 0, x1, DIM, (ll)SEQ * DIM, 0,
        slots, DIM, (ll)ES * DIM, 0,
        ES, DIM, SEQ, 1);

    // 12: hmid = gelu(slots @ We1 + be1), batched over (b,e)
    gemm_nn<<<dim3(64, 8, BATCH * NEXP), blk, 0, stream>>>(
        slots, DIM, (ll)NEXP * NSLOT * DIM, (ll)NSLOT * DIM,
        We1, HID, 0, (ll)DIM * HID,
        be1, 0, HID,
        hmid, HID, (ll)NEXP * NSLOT * HID, (ll)NSLOT * HID,
        NSLOT, HID, DIM, NEXP, 1);

    // 13: ymoe = hmid @ We2 + be2
    gemm_nn<<<dim3(16, 8, BATCH * NEXP), blk, 0, stream>>>(
        hmid, HID, (ll)NEXP * NSLOT * HID, (ll)NSLOT * HID,
        We2, DIM, 0, (ll)HID * DIM,
        be2, 0, DIM,
        ymoe, DIM, (ll)NEXP * NSLOT * DIM, (ll)NSLOT * DIM,
        NSLOT, DIM, HID, NEXP, 0);

    // 14: moe_out[b] = combine[b] @ ymoe[b]
    gemm_nn<<<dim3(16, 16, BATCH), blk, 0, stream>>>(
        comb, ES, (ll)SEQ * ES, 0, ymoe, DIM, (ll)ES * DIM, 0,
        nullptr, 0, 0,
        moe, DIM, (ll)SEQ * DIM, 0,
        SEQ, DIM, ES, 1, 0);

    // 15: y = LN(moe + 2*x1)  ->  d_out
    ln_kernel<<<dim3(NTOK), blk, 0, stream>>>(moe, x1, 2.0f, g2, b2, out_y);
}

// Round 2
// 1203.976 us; speedup vs baseline: 2.6228x; 2.6228x over previous
//
#include <hip/hip_runtime.h>
#include <math.h>

// Problem constants
#define BATCH 4
#define SEQ   1024
#define DIM   1024
#define HEADS 16
#define HD    64
#define NEXP  2
#define NSLOT 512
#define ES    1024       // NEXP*NSLOT
#define HID   4096
#define LNEPS 1e-5f
#define NTOK  (BATCH*SEQ)

typedef long long ll;
typedef unsigned short ushort;
typedef unsigned int uint;
typedef __attribute__((ext_vector_type(8))) short short8;   // 8 bf16 (4 VGPRs)
typedef __attribute__((ext_vector_type(4))) float f32x4;    // MFMA accum

__device__ __forceinline__ ushort f2b(float f) {            // fp32 -> bf16 RNE
    uint u = __builtin_bit_cast(uint, f);
    u += 0x7FFFu + ((u >> 16) & 1u);
    return (ushort)(u >> 16);
}
__device__ __forceinline__ float b2f(ushort h) {
    uint u = ((uint)h) << 16;
    return __builtin_bit_cast(float, u);
}
__device__ __forceinline__ uint pk(float a, float b) {
    return (uint)f2b(a) | ((uint)f2b(b) << 16);
}
__device__ __forceinline__ float gelu_f(float v) {
    float x3 = v * v * v;
    return 0.5f * v * (1.f + tanhf(0.7978845608028654f * (v + 0.044715f * x3)));
}

// Stage 16 contiguous elements (fp32->bf16 convert, or bf16 copy) into LDS.
template<typename T>
__device__ __forceinline__ void stage16(ushort* dst, const T* src) {
    if constexpr (sizeof(T) == 2) {
        const uint4* s = reinterpret_cast<const uint4*>(src);
        *reinterpret_cast<uint4*>(dst)     = s[0];
        *reinterpret_cast<uint4*>(dst + 8) = s[1];
    } else {
        const float4* s = reinterpret_cast<const float4*>(src);
        float4 f0 = s[0], f1 = s[1], f2 = s[2], f3 = s[3];
        uint4 w0, w1;
        w0.x = pk(f0.x, f0.y); w0.y = pk(f0.z, f0.w);
        w0.z = pk(f1.x, f1.y); w0.w = pk(f1.z, f1.w);
        w1.x = pk(f2.x, f2.y); w1.y = pk(f2.z, f2.w);
        w1.z = pk(f3.x, f3.y); w1.w = pk(f3.z, f3.w);
        *reinterpret_cast<uint4*>(dst)     = w0;
        *reinterpret_cast<uint4*>(dst + 8) = w1;
    }
}

// Stage 8 k-strided elements (one column segment of row-major B) into LDS.
template<typename T>
__device__ __forceinline__ void stage8s(ushort* dst, const T* src, int ldb) {
    ushort h[8];
    #pragma unroll
    for (int j = 0; j < 8; j++) {
        if constexpr (sizeof(T) == 2) h[j] = (ushort)src[(ll)j * ldb];
        else                          h[j] = f2b(src[(ll)j * ldb]);
    }
    uint4 w;
    w.x = (uint)h[0] | ((uint)h[1] << 16);
    w.y = (uint)h[2] | ((uint)h[3] << 16);
    w.z = (uint)h[4] | ((uint)h[5] << 16);
    w.w = (uint)h[6] | ((uint)h[7] << 16);
    *reinterpret_cast<uint4*>(dst) = w;
}

// ---------------------------------------------------------------------------
// MFMA bf16 GEMM: C[M,N] = act(alpha * A@B + bias)
//   WR x WC waves, each computing (MI*16) x (NI*16); BM = WR*MI*16 == 128.
//   TA/TB/TC in {float, ushort(bf16)}.  BT: 0 = B[K][N] (NN), 1 = B[N][K] (ABT).
//   LDS row stride 40 bf16 (80B): 16B-aligned rows, <=2-way banks on b128.
//   Batched via z = z1*Z2+z2 with per-operand stride pairs.
// ---------------------------------------------------------------------------
template<int WR, int WC, int MI, int NI, typename TA, typename TB, typename TC,
         int BT, int ACT>
__global__ __launch_bounds__(256) void gemm_mfma(
    const TA* __restrict__ A, int lda, ll sA1, ll sA2,
    const TB* __restrict__ B, int ldb, ll sB1, ll sB2,
    const float* __restrict__ bias, ll sb1, ll sb2,
    TC* __restrict__ C, int ldc, ll sC1, ll sC2,
    int K, int Z2, float alpha)
{
    constexpr int BM = WR * MI * 16;   // == 128
    constexpr int BN = WC * NI * 16;   // 128 or 64
    __shared__ ushort As[128 * 40];
    __shared__ ushort Bs[BN * 40];

    const int z1 = blockIdx.z / Z2, z2 = blockIdx.z % Z2;
    A += z1 * sA1 + z2 * sA2;
    B += z1 * sB1 + z2 * sB2;
    C += z1 * sC1 + z2 * sC2;

    const int t = threadIdx.x;
    const int m0 = blockIdx.y * BM, n0 = blockIdx.x * BN;

    // A staging: 128 rows x 32 k, 16 contiguous k per thread
    const int am = t >> 1, ak = (t & 1) * 16;

    const int lane = t & 63, wave = t >> 6;
    const int quad = lane >> 4, l16 = lane & 15;
    const int wm = wave / WC, wn = wave % WC;

    f32x4 acc[MI][NI] = {};

    for (int k0 = 0; k0 < K; k0 += 32) {
        stage16<TA>(&As[am * 40 + ak], A + (ll)(m0 + am) * lda + k0 + ak);
        if constexpr (BT == 1) {
            // B[N][K] row-major: same pattern as A
            stage16<TB>(&Bs[am * 40 + ak], B + (ll)(n0 + am) * ldb + k0 + ak);
        } else if constexpr (BN == 128) {
            const int bn = t & 127, kb = (t >> 7) * 16;
            stage8s<TB>(&Bs[bn * 40 + kb],     B + (ll)(k0 + kb) * ldb + n0 + bn, ldb);
            stage8s<TB>(&Bs[bn * 40 + kb + 8], B + (ll)(k0 + kb + 8) * ldb + n0 + bn, ldb);
        } else {  // BN == 64
            const int bn = t & 63, kb = (t >> 6) * 8;
            stage8s<TB>(&Bs[bn * 40 + kb], B + (ll)(k0 + kb) * ldb + n0 + bn, ldb);
        }
        __syncthreads();

        short8 a[MI], b[NI];
        #pragma unroll
        for (int mi = 0; mi < MI; mi++)
            a[mi] = *reinterpret_cast<const short8*>(
                &As[(wm * MI * 16 + mi * 16 + l16) * 40 + quad * 8]);
        #pragma unroll
        for (int ni = 0; ni < NI; ni++)
            b[ni] = *reinterpret_cast<const short8*>(
                &Bs[(wn * NI * 16 + ni * 16 + l16) * 40 + quad * 8]);
        #pragma unroll
        for (int mi = 0; mi < MI; mi++)
            #pragma unroll
            for (int ni = 0; ni < NI; ni++)
                acc[mi][ni] = __builtin_amdgcn_mfma_f32_16x16x32_bf16(
                    a[mi], b[ni], acc[mi][ni], 0, 0, 0);
        __syncthreads();
    }

    const float* bz = bias ? (bias + z1 * sb1 + z2 * sb2) : nullptr;
    #pragma unroll
    for (int mi = 0; mi < MI; mi++) {
        #pragma unroll
        for (int ni = 0; ni < NI; ni++) {
            const int row = m0 + wm * MI * 16 + mi * 16 + quad * 4;
            const int col = n0 + wn * NI * 16 + ni * 16 + l16;
            const float bv = bz ? bz[col] : 0.f;
            #pragma unroll
            for (int r = 0; r < 4; r++) {
                float v = alpha * acc[mi][ni][r] + bv;
                if (ACT) v = gelu_f(v);
                if constexpr (sizeof(TC) == 2)
                    C[(ll)(row + r) * ldc + col] = f2b(v);
                else
                    C[(ll)(row + r) * ldc + col] = v;
            }
        }
    }
}

// ---------------------------------------------------------------------------
// Attention softmax over m.  p: bf16 (b,h,n,m), normalized in place (for AV)
// and ALSO written as fp32 attn_out in (b,n,m,h) layout.
// grid (SEQ, BATCH); 4 waves x 4 passes over heads; wave-only reduction.
// ---------------------------------------------------------------------------
__global__ __launch_bounds__(256) void attn_softmax(
    ushort* __restrict__ p, float* __restrict__ attn_out)
{
    __shared__ float tile[16 * 1024];
    const int n = blockIdx.x, b = blockIdx.y;
    const int lane = threadIdx.x & 63, w = threadIdx.x >> 6;
    for (int hq = 0; hq < 4; hq++) {
        int h = hq * 4 + w;
        ushort* row = p + ((ll)(b * HEADS + h) * SEQ + n) * SEQ;
        float v[16];
        float m = -3.0e38f;
        #pragma unroll
        for (int j = 0; j < 16; j++) { v[j] = b2f(row[lane + 64 * j]); m = fmaxf(m, v[j]); }
        #pragma unroll
        for (int o = 32; o; o >>= 1) m = fmaxf(m, __shfl_xor(m, o));
        float s = 0.f;
        #pragma unroll
        for (int j = 0; j < 16; j++) { v[j] = __expf(v[j] - m); s += v[j]; }
        #pragma unroll
        for (int o = 32; o; o >>= 1) s += __shfl_xor(s, o);
        float inv = 1.f / s;
        int sw = (h & 7) << 2;
        #pragma unroll
        for (int j = 0; j < 16; j++) {
            float e = v[j] * inv;
            int mm = lane + 64 * j;
            row[mm] = f2b(e);
            tile[h * 1024 + (mm ^ sw)] = e;
        }
    }
    __syncthreads();
    float* outp = attn_out + ((ll)b * SEQ + n) * SEQ * HEADS;
    for (int o = threadIdx.x; o < SEQ * HEADS; o += 256) {
        int mm = o >> 4, h = o & 15;
        outp[o] = tile[h * 1024 + (mm ^ ((h & 7) << 2))];
    }
}

// ---------------------------------------------------------------------------
// LayerNorm: out_row = LN(a_row + coef*b_row) * g + beta    (rows of DIM)
// ---------------------------------------------------------------------------
__global__ __launch_bounds__(256) void ln_kernel(
    const float* __restrict__ a, const float* __restrict__ b, float coef,
    const float* __restrict__ g, const float* __restrict__ beta,
    float* __restrict__ out)
{
    const int row = blockIdx.x;
    const float* ar = a + (ll)row * DIM;
    const float* br = b + (ll)row * DIM;
    float v[4];
    float s1 = 0.f, s2 = 0.f;
    #pragma unroll
    for (int j = 0; j < 4; j++) {
        int i = threadIdx.x + 256 * j;
        v[j] = ar[i] + coef * br[i];
        s1 += v[j]; s2 += v[j] * v[j];
    }
    __shared__ float red[8];
    #pragma unroll
    for (int o = 32; o; o >>= 1) { s1 += __shfl_xor(s1, o); s2 += __shfl_xor(s2, o); }
    int w = threadIdx.x >> 6;
    if ((threadIdx.x & 63) == 0) { red[w] = s1; red[4 + w] = s2; }
    __syncthreads();
    s1 = red[0] + red[1] + red[2] + red[3];
    s2 = red[4] + red[5] + red[6] + red[7];
    float mu = s1 * (1.f / DIM);
    float var = s2 * (1.f / DIM) - mu * mu;
    float rs = rsqrtf(var + LNEPS);
    float* orow = out + (ll)row * DIM;
    #pragma unroll
    for (int j = 0; j < 4; j++) {
        int i = threadIdx.x + 256 * j;
        orow[i] = (v[j] - mu) * rs * g[i] + beta[i];
    }
}

// ---------------------------------------------------------------------------
// dispatch = softmax over n of logits (b,n,es), written TRANSPOSED as
// dispT[b][es][n] in bf16 (row-major k=n contiguous -> standard GEMM A).
// grid (BATCH, 16); block = 64 cols x 4 row-groups. Reads L coalesced 3x,
// writes dispT scattered once (8 MB total).
// ---------------------------------------------------------------------------
__global__ __launch_bounds__(256) void col_softmax(
    const float* __restrict__ logits, ushort* __restrict__ dispT)
{
    const int b = blockIdx.x, cc = blockIdx.y;
    const int cl = threadIdx.x & 63;
    const int c = cc * 64 + cl;
    const int rg = threadIdx.x >> 6;
    const float* L = logits + (ll)b * SEQ * ES + c;
    ushort* DT = dispT + (ll)b * ES * SEQ + (ll)c * SEQ;
    __shared__ float red[4][64];
    float m = -3.0e38f;
    for (int n = rg; n < SEQ; n += 4) m = fmaxf(m, L[(ll)n * ES]);
    red[rg][cl] = m;
    __syncthreads();
    m = fmaxf(fmaxf(red[0][cl], red[1][cl]), fmaxf(red[2][cl], red[3][cl]));
    __syncthreads();
    float s = 0.f;
    for (int n = rg; n < SEQ; n += 4) s += __expf(L[(ll)n * ES] - m);
    red[rg][cl] = s;
    __syncthreads();
    s = red[0][cl] + red[1][cl] + red[2][cl] + red[3][cl];
    float inv = 1.f / s;
    for (int n = rg; n < SEQ; n += 4)
        DT[n] = f2b(__expf(L[(ll)n * ES] - m) * inv);
}

// combine = softmax over es (rows of 1024), bf16 out
__global__ __launch_bounds__(256) void row_softmax(
    const float* __restrict__ logits, ushort* __restrict__ comb)
{
    const int row = blockIdx.x;
    const float* L = logits + (ll)row * ES;
    ushort* O = comb + (ll)row * ES;
    float v[4];
    float m = -3.0e38f;
    #pragma unroll
    for (int j = 0; j < 4; j++) { v[j] = L[threadIdx.x + 256 * j]; m = fmaxf(m, v[j]); }
    __shared__ float red[8];
    #pragma unroll
    for (int o = 32; o; o >>= 1) m = fmaxf(m, __shfl_xor(m, o));
    int w = threadIdx.x >> 6;
    if ((threadIdx.x & 63) == 0) red[w] = m;
    __syncthreads();
    m = fmaxf(fmaxf(red[0], red[1]), fmaxf(red[2], red[3]));
    __syncthreads();
    float s = 0.f;
    #pragma unroll
    for (int j = 0; j < 4; j++) { v[j] = __expf(v[j] - m); s += v[j]; }
    #pragma unroll
    for (int o = 32; o; o >>= 1) s += __shfl_xor(s, o);
    if ((threadIdx.x & 63) == 0) red[4 + w] = s;
    __syncthreads();
    s = red[4] + red[5] + red[6] + red[7];
    float inv = 1.f / s;
    #pragma unroll
    for (int j = 0; j < 4; j++) O[threadIdx.x + 256 * j] = f2b(v[j] * inv);
}

// ---------------------------------------------------------------------------
extern "C" void kernel_launch(void* const* d_in, const int* in_sizes, int n_in,
                              void* d_out, int out_size, void* d_ws, size_t ws_size,
                              hipStream_t stream)
{
    const float* x   = (const float*)d_in[0];
    const float* Wq  = (const float*)d_in[1];
    const float* bq  = (const float*)d_in[2];
    const float* Wkv = (const float*)d_in[3];
    const float* bkv = (const float*)d_in[4];
    const float* Wp  = (const float*)d_in[5];
    const float* bp  = (const float*)d_in[6];
    const float* g1  = (const float*)d_in[7];
    const float* b1  = (const float*)d_in[8];
    const float* phi = (const float*)d_in[9];
    const float* We1 = (const float*)d_in[10];
    const float* be1 = (const float*)d_in[11];
    const float* We2 = (const float*)d_in[12];
    const float* be2 = (const float*)d_in[13];
    const float* g2  = (const float*)d_in[14];
    const float* b2  = (const float*)d_in[15];

    float* out_y    = (float*)d_out;
    float* out_attn = out_y + (ll)BATCH * SEQ * DIM;

    // Workspace layout (float offsets), peak 48M floats = 192 MB:
    const ll M1 = 1024 * 1024;
    float*  ws    = (float*)d_ws;
    float*  kvb   = ws;                        // [0,8M) fp32 kv
    ushort* p_bf  = (ushort*)(ws + 8 * M1);    // [8M,40M): 64M bf16 scores
    float*  q     = ws + 40 * M1;              // [40M,44M)
    float*  ao    = ws + 44 * M1;              // [44M,48M)
    // phase 2 (p/q regions dead):
    float*  x1    = ws + 8 * M1;               // [8M,12M)
    float*  logit = ws + 12 * M1;              // [12M,16M)
    ushort* dispT = (ushort*)(ws + 16 * M1);   // [16M,18M): 4M bf16
    ushort* comb  = (ushort*)(ws + 18 * M1);   // [18M,20M)
    ushort* slots = (ushort*)(ws + 20 * M1);   // [20M,22M): 4M bf16
    ushort* hmid  = (ushort*)(ws + 22 * M1);   // [22M,30M): 16M bf16
    ushort* ymoe  = (ushort*)(ws + 30 * M1);   // [30M,32M): 4M bf16
    float*  moe   = ws + 32 * M1;              // [32M,36M)
    float*  po    = ws + 40 * M1;              // q region

    dim3 blk(256);

    // 1-2: QKV projections (fp32 in, fp32 out)
    gemm_mfma<2,2,4,4,float,float,float,0,0><<<dim3(8, 32, 1), blk, 0, stream>>>(
        x, DIM, 0, 0, Wq, DIM, 0, 0, bq, 0, 0, q, DIM, 0, 0, DIM, 1, 1.f);
    gemm_mfma<2,2,4,4,float,float,float,0,0><<<dim3(16, 32, 1), blk, 0, stream>>>(
        x, DIM, 0, 0, Wkv, 2 * DIM, 0, 0, bkv, 0, 0, kvb, 2 * DIM, 0, 0, DIM, 1, 1.f);

    // 3: scores p[b,h,n,m] = 0.125 * q_bh @ k_bh^T  (bf16 out), all b,h at once
    gemm_mfma<2,2,4,4,float,float,ushort,1,0><<<dim3(8, 8, BATCH * HEADS), blk, 0, stream>>>(
        q, DIM, (ll)SEQ * DIM, 64,
        kvb, 2 * DIM, (ll)SEQ * 2 * DIM, 64,
        nullptr, 0, 0,
        p_bf, SEQ, (ll)HEADS * SEQ * SEQ, (ll)SEQ * SEQ,
        HD, HEADS, 0.125f);

    // 4: softmax over m (in-place bf16) + fp32 bnmh attn output
    attn_softmax<<<dim3(SEQ, BATCH), blk, 0, stream>>>(p_bf, out_attn);

    // 5: ao[b,n,h*64+d] = p_bh @ v_bh   (BN=64 config)
    gemm_mfma<4,1,2,4,ushort,float,float,0,0><<<dim3(1, 8, BATCH * HEADS), blk, 0, stream>>>(
        p_bf, SEQ, (ll)HEADS * SEQ * SEQ, (ll)SEQ * SEQ,
        kvb + DIM, 2 * DIM, (ll)SEQ * 2 * DIM, 64,
        nullptr, 0, 0,
        ao, DIM, (ll)SEQ * DIM, 64,
        SEQ, HEADS, 1.f);

    // 6: output projection
    gemm_mfma<2,2,4,4,float,float,float,0,0><<<dim3(8, 32, 1), blk, 0, stream>>>(
        ao, DIM, 0, 0, Wp, DIM, 0, 0, bp, 0, 0, po, DIM, 0, 0, DIM, 1, 1.f);
    // 7: x1 = LN(po + x)
    ln_kernel<<<dim3(NTOK), blk, 0, stream>>>(po, x, 1.0f, g1, b1, x1);

    // 8: moe logits = x1 @ phi (fp32 out for softmaxes)
    gemm_mfma<2,2,4,4,float,float,float,0,0><<<dim3(8, 32, 1), blk, 0, stream>>>(
        x1, DIM, 0, 0, phi, ES, 0, 0, nullptr, 0, 0, logit, ES, 0, 0, DIM, 1, 1.f);
    // 9-10: dispatch (transposed bf16) and combine (bf16) softmaxes
    col_softmax<<<dim3(BATCH, 16), blk, 0, stream>>>(logit, dispT);
    row_softmax<<<dim3(NTOK), blk, 0, stream>>>(logit, comb);

    // 11: slots[b] = dispT[b] @ x1[b]   (ES x DIM, K=SEQ)
    gemm_mfma<2,2,4,4,ushort,float,ushort,0,0><<<dim3(8, 8, BATCH), blk, 0, stream>>>(
        dispT, SEQ, (ll)ES * SEQ, 0,
        x1, DIM, (ll)SEQ * DIM, 0,
        nullptr, 0, 0,
        slots, DIM, (ll)ES * DIM, 0,
        SEQ, 1, 1.f);

    // 12: hmid = gelu(slots @ We1 + be1), z = b*NEXP+e
    gemm_mfma<2,2,4,4,ushort,float,ushort,0,1><<<dim3(32, 4, BATCH * NEXP), blk, 0, stream>>>(
        slots, DIM, (ll)NEXP * NSLOT * DIM, (ll)NSLOT * DIM,
        We1, HID, 0, (ll)DIM * HID,
        be1, 0, HID,
        hmid, HID, (ll)NEXP * NSLOT * HID, (ll)NSLOT * HID,
        DIM, NEXP, 1.f);

    // 13: ymoe = hmid @ We2 + be2
    gemm_mfma<2,2,4,4,ushort,float,ushort,0,0><<<dim3(8, 4, BATCH * NEXP), blk, 0, stream>>>(
        hmid, HID, (ll)NEXP * NSLOT * HID, (ll)NSLOT * HID,
        We2, DIM, 0, (ll)HID * DIM,
        be2, 0, DIM,
        ymoe, DIM, (ll)NEXP * NSLOT * DIM, (ll)NSLOT * DIM,
        HID, NEXP, 1.f);

    // 14: moe[b] = comb[b] @ ymoe[b]
    gemm_mfma<2,2,4,4,ushort,ushort,float,0,0><<<dim3(8, 8, BATCH), blk, 0, stream>>>(
        comb, ES, (ll)SEQ * ES, 0,
        ymoe, DIM, (ll)ES * DIM, 0,
        nullptr, 0, 0,
        moe, DIM, (ll)SEQ * DIM, 0,
        ES, 1, 1.f);

    // 15: y = LN(moe + 2*x1)
    ln_kernel<<<dim3(NTOK), blk, 0, stream>>>(moe, x1, 2.0f, g2, b2, out_y);
}